// Round 17
// baseline (182.958 us; speedup 1.0000x reference)
//
#include <hip/hip_runtime.h>

#define NH 16
#define FEAT 16
#define HD 33
#define DM 528
#define WIN 64
#define EPSF 1e-9f
#define K1C (0.17407765595569785f * 1.4426950408889634f)
#define KP 544               // padded K for projections
#define KSPLIT 1632          // 3*544 for hi/lo split GEMM
#define NPROJ 2112           // 528 win-q + 528 win-k + 528 win-v + 528 lin-v
#define KOUT 1056            // 528 lin + 528 win
#define OPS 4352             // Opart per-part stride (128 rows x 34)
#define NCH 16               // lin_kv chunks
#define OPSLOTS 4            // max split parts per q-tile

typedef float f32x4 __attribute__((ext_vector_type(4)));
typedef short short8 __attribute__((ext_vector_type(8)));

__device__ inline ushort f2bf(float f) {
  uint u = __float_as_uint(f);
  uint r = u + 0x7fffu + ((u >> 16) & 1u);
  return (ushort)(r >> 16);
}
__device__ inline ushort f2bf_tr(float f) { return (ushort)(__float_as_uint(f) >> 16); }
__device__ inline float bf2f(ushort u) { return __uint_as_float(((uint)u) << 16); }

// ---------------- fused prep: x hi/lo cvt + weight packs + qk zero ---------------
__global__ __launch_bounds__(256) void prep_all(const float* __restrict__ x,
                                                const float* __restrict__ Wq_lin,
                                                const float* __restrict__ Wk_lin,
                                                const float* __restrict__ Wv_lin,
                                                const float* __restrict__ Wo_lin,
                                                const float* __restrict__ Wq_win,
                                                const float* __restrict__ Wk_win,
                                                const float* __restrict__ Wv_win,
                                                const float* __restrict__ Wo_win,
                                                ushort* __restrict__ xhi,
                                                ushort* __restrict__ xlo,
                                                ushort* __restrict__ Wqks,
                                                ushort* __restrict__ WprojT,
                                                ushort* __restrict__ WoT2,
                                                float* __restrict__ qk, int M) {
  const int stride = gridDim.x * 256;
  const int tid0 = blockIdx.x * 256 + threadIdx.x;
  for (int j = tid0; j < M * 68; j += stride) {
    int row = j / 68, c8 = (j - row * 68) * 8;
    short8 h8, l8;
    if (c8 < DM) {
      float4 f0 = *(const float4*)&x[(size_t)row * DM + c8];
      float4 f1 = *(const float4*)&x[(size_t)row * DM + c8 + 4];
      float vv[8] = {f0.x, f0.y, f0.z, f0.w, f1.x, f1.y, f1.z, f1.w};
#pragma unroll
      for (int z = 0; z < 8; ++z) {
        ushort h = f2bf(vv[z]);
        h8[z] = (short)h;
        l8[z] = (short)f2bf(vv[z] - bf2f(h));
      }
    } else {
      h8 = (short8){0, 0, 0, 0, 0, 0, 0, 0};
      l8 = h8;
    }
    *(short8*)&xhi[(size_t)row * KP + c8] = h8;
    *(short8*)&xlo[(size_t)row * KP + c8] = l8;
  }
  for (int i = tid0; i < M * 128; i += stride)
    ((float4*)qk)[i] = make_float4(0.f, 0.f, 0.f, 0.f);
  for (int i = tid0; i < 512 * KSPLIT; i += stride) {
    int n = i / KSPLIT, kp = i - n * KSPLIT;
    int seg = kp / KP, kk = kp - seg * KP;
    float v = 0.f;
    if (kk < DM) v = (n < 256) ? Wq_lin[(size_t)kk * 256 + n] : Wk_lin[(size_t)kk * 256 + (n - 256)];
    ushort h = f2bf(v);
    if (seg == 2) h = f2bf(v - bf2f(h));
    Wqks[i] = h;
  }
  for (int i = tid0; i < NPROJ * KP; i += stride) {
    int n = i / KP, k = i - n * KP;
    float v = 0.f;
    if (k < DM) {
      if (n < DM) v = Wq_win[(size_t)k * DM + n];
      else if (n < 2 * DM) v = Wk_win[(size_t)k * DM + (n - DM)] * K1C;
      else if (n < 3 * DM) v = Wv_win[(size_t)k * DM + (n - 2 * DM)];
      else v = Wv_lin[(size_t)k * DM + (n - 3 * DM)];
    }
    WprojT[i] = f2bf(v);
  }
  for (int i = tid0; i < DM * KOUT; i += stride) {
    int n = i / KOUT, k = i - n * KOUT;
    float v = (k < DM) ? Wo_lin[(size_t)k * DM + n] : Wo_win[(size_t)(k - DM) * DM + n];
    WoT2[i] = f2bf(v);
  }
}

// ---------------- merged projection GEMMs (one launch) ---------------------------
// y < 17 : win q/k/v + lin v projection;  y in 17..28: lin q/k split, one K-segment
__global__ __launch_bounds__(256) void proj_fused(const ushort* __restrict__ xhi,
                                                  const ushort* __restrict__ xlo,
                                                  const ushort* __restrict__ Wqks,
                                                  const ushort* __restrict__ WprojT,
                                                  float* __restrict__ qk,
                                                  ushort* __restrict__ qkvw,
                                                  float* __restrict__ v_lin,
                                                  const int* __restrict__ maskp,
                                                  int S) {
  __shared__ ushort As[128][36];
  __shared__ ushort Bs[128][36];
  const int bm = blockIdx.x * 128;
  const int tid = threadIdx.x;
  const int lane = tid & 63, w = tid >> 6;
  const int lo = lane & 15, hi = lane >> 4;
  const int wr = w >> 1, wc = w & 1;
  const short8 zv = {0, 0, 0, 0, 0, 0, 0, 0};
  f32x4 acc[4][4];
#pragma unroll
  for (int mb = 0; mb < 4; ++mb)
#pragma unroll
    for (int nb = 0; nb < 4; ++nb) acc[mb][nb] = (f32x4){0.f, 0.f, 0.f, 0.f};

  if (blockIdx.y < 17) {
    const int bn = blockIdx.y * 128;
    for (int k0 = 0; k0 < KP; k0 += 32) {
      short8 a_ld[2], b_ld[2];
#pragma unroll
      for (int p = 0; p < 2; ++p) {
        int c = tid + p * 256;
        int row = c >> 2, cc = c & 3;
        a_ld[p] = *(const short8*)&xhi[(size_t)(bm + row) * KP + k0 + cc * 8];
        int bnr = bn + row;
        b_ld[p] = (bnr < NPROJ) ? *(const short8*)&WprojT[(size_t)bnr * KP + k0 + cc * 8] : zv;
      }
      __syncthreads();
#pragma unroll
      for (int p = 0; p < 2; ++p) {
        int c = tid + p * 256;
        int row = c >> 2, cc = c & 3;
        *(short8*)&As[row][cc * 8] = a_ld[p];
        *(short8*)&Bs[row][cc * 8] = b_ld[p];
      }
      __syncthreads();
      short8 afr[4], bfr[4];
#pragma unroll
      for (int mb = 0; mb < 4; ++mb) afr[mb] = *(const short8*)&As[wr * 64 + 16 * mb + lo][8 * hi];
#pragma unroll
      for (int nb = 0; nb < 4; ++nb) bfr[nb] = *(const short8*)&Bs[wc * 64 + 16 * nb + lo][8 * hi];
#pragma unroll
      for (int mb = 0; mb < 4; ++mb)
#pragma unroll
        for (int nb = 0; nb < 4; ++nb)
          acc[mb][nb] = __builtin_amdgcn_mfma_f32_16x16x32_bf16(afr[mb], bfr[nb], acc[mb][nb], 0, 0, 0);
    }
#pragma unroll
    for (int nb = 0; nb < 4; ++nb) {
      const int col = bn + wc * 64 + 16 * nb + lo;
      if (col >= NPROJ) continue;
      const int seg = col / DM;          // 0=win q 1=win k 2=win v 3=lin v
      const int cc = col - seg * DM;
      if (seg == 3) {
#pragma unroll
        for (int mb = 0; mb < 4; ++mb)
#pragma unroll
          for (int r = 0; r < 4; ++r) {
            int row = bm + wr * 64 + 16 * mb + 4 * hi + r;
            v_lin[(size_t)row * DM + cc] = acc[mb][nb][r];
          }
      } else {
        const uint h = ((uint)cc * 993u) >> 15;
        const int e = cc - (int)h * 33;
        ushort* dst = qkvw + (size_t)seg * (32u * (uint)S * 40u);
#pragma unroll
        for (int mb = 0; mb < 4; ++mb)
#pragma unroll
          for (int r = 0; r < 4; ++r) {
            int row = bm + wr * 64 + 16 * mb + 4 * hi + r;
            int b = (row >= S) ? 1 : 0;
            int nn = row - b * S;
            float val = acc[mb][nb][r];
            if (seg == 2) {
              size_t tb = (size_t)(b * NH + (int)h) * 40;
              dst[(tb + e) * S + nn] = f2bf(val);
              if (e == 0) {
                dst[(tb + 33) * S + nn] = 0x3F80;
#pragma unroll
                for (int z = 34; z < 40; ++z) dst[(tb + z) * S + nn] = 0;
              }
            } else {
              size_t base = ((size_t)(b * NH + (int)h) * S + nn) * 40;
              dst[base + e] = f2bf(val);
              if (e == 0) {
                ushort pad33 = (seg == 0) ? (ushort)0x3F80
                                          : (maskp[row] ? (ushort)0 : f2bf(-1e30f));
                dst[base + 33] = pad33;
#pragma unroll
                for (int z = 34; z < 40; ++z) dst[base + z] = 0;
              }
            }
          }
      }
    }
  } else {
    const int yy = blockIdx.y - 17;      // 0..11
    const int seg = yy >> 2;             // K-segment 0..2
    const int bn = (yy & 3) * 128;
    const ushort* xsrc = (seg == 1) ? xlo : xhi;
    const int kb = seg * KP;
    for (int k0 = 0; k0 < KP; k0 += 32) {
      short8 a_ld[2], b_ld[2];
#pragma unroll
      for (int p = 0; p < 2; ++p) {
        int c = tid + p * 256;
        int row = c >> 2, cc = c & 3;
        a_ld[p] = *(const short8*)&xsrc[(size_t)(bm + row) * KP + k0 + cc * 8];
        b_ld[p] = *(const short8*)&Wqks[(size_t)(bn + row) * KSPLIT + kb + k0 + cc * 8];
      }
      __syncthreads();
#pragma unroll
      for (int p = 0; p < 2; ++p) {
        int c = tid + p * 256;
        int row = c >> 2, cc = c & 3;
        *(short8*)&As[row][cc * 8] = a_ld[p];
        *(short8*)&Bs[row][cc * 8] = b_ld[p];
      }
      __syncthreads();
      short8 afr[4], bfr[4];
#pragma unroll
      for (int mb = 0; mb < 4; ++mb) afr[mb] = *(const short8*)&As[wr * 64 + 16 * mb + lo][8 * hi];
#pragma unroll
      for (int nb = 0; nb < 4; ++nb) bfr[nb] = *(const short8*)&Bs[wc * 64 + 16 * nb + lo][8 * hi];
#pragma unroll
      for (int mb = 0; mb < 4; ++mb)
#pragma unroll
        for (int nb = 0; nb < 4; ++nb)
          acc[mb][nb] = __builtin_amdgcn_mfma_f32_16x16x32_bf16(afr[mb], bfr[nb], acc[mb][nb], 0, 0, 0);
    }
#pragma unroll
    for (int mb = 0; mb < 4; ++mb)
#pragma unroll
      for (int nb = 0; nb < 4; ++nb) {
        int col = bn + wc * 64 + 16 * nb + lo;
#pragma unroll
        for (int r = 0; r < 4; ++r) {
          int row = bm + wr * 64 + 16 * mb + 4 * hi + r;
          atomicAdd(&qk[(size_t)row * 512 + col], acc[mb][nb][r]);
        }
      }
  }
}

// ---------------- final output GEMM: BM=64 x BN=128 ------------------------------
__global__ __launch_bounds__(256) void gemm_out(const ushort* __restrict__ A,
                                                const ushort* __restrict__ Bt,
                                                float* __restrict__ C, int S) {
  __shared__ ushort As[64][36];
  __shared__ ushort Bs[128][36];
  const int bm = blockIdx.x * 64, bn = blockIdx.y * 128;
  const int tid = threadIdx.x;
  const int lane = tid & 63, w = tid >> 6;
  const int lo = lane & 15, hi = lane >> 4;
  const int wr = w & 1, wc = w >> 1;
  f32x4 acc[2][4];
#pragma unroll
  for (int mb = 0; mb < 2; ++mb)
#pragma unroll
    for (int nb = 0; nb < 4; ++nb) acc[mb][nb] = (f32x4){0.f, 0.f, 0.f, 0.f};
  const short8 zv = {0, 0, 0, 0, 0, 0, 0, 0};

  for (int k0 = 0; k0 < KOUT; k0 += 32) {
    short8 a_ld, b_ld[2];
    {
      int row = tid >> 2, cc = tid & 3;
      a_ld = *(const short8*)&A[(size_t)(bm + row) * KOUT + k0 + cc * 8];
    }
#pragma unroll
    for (int p = 0; p < 2; ++p) {
      int c = tid + p * 256;
      int row = c >> 2, cc = c & 3;
      int bnr = bn + row;
      b_ld[p] = (bnr < DM) ? *(const short8*)&Bt[(size_t)bnr * KOUT + k0 + cc * 8] : zv;
    }
    __syncthreads();
    {
      int row = tid >> 2, cc = tid & 3;
      *(short8*)&As[row][cc * 8] = a_ld;
    }
#pragma unroll
    for (int p = 0; p < 2; ++p) {
      int c = tid + p * 256;
      int row = c >> 2, cc = c & 3;
      *(short8*)&Bs[row][cc * 8] = b_ld[p];
    }
    __syncthreads();
    short8 afr[2], bfr[4];
#pragma unroll
    for (int mb = 0; mb < 2; ++mb) afr[mb] = *(const short8*)&As[wr * 32 + 16 * mb + lo][8 * hi];
#pragma unroll
    for (int nb = 0; nb < 4; ++nb) bfr[nb] = *(const short8*)&Bs[wc * 64 + 16 * nb + lo][8 * hi];
#pragma unroll
    for (int mb = 0; mb < 2; ++mb)
#pragma unroll
      for (int nb = 0; nb < 4; ++nb)
        acc[mb][nb] = __builtin_amdgcn_mfma_f32_16x16x32_bf16(afr[mb], bfr[nb], acc[mb][nb], 0, 0, 0);
  }
#pragma unroll
  for (int nb = 0; nb < 4; ++nb) {
    const int col = bn + wc * 64 + 16 * nb + lo;
    if (col >= DM) continue;
#pragma unroll
    for (int mb = 0; mb < 2; ++mb)
#pragma unroll
      for (int r = 0; r < 4; ++r) {
        int row = bm + wr * 32 + 16 * mb + 4 * hi + r;
        C[(size_t)row * DM + col] = acc[mb][nb][r];
      }
  }
}

__global__ __launch_bounds__(256) void lin_red(const float* __restrict__ kvp,
                                               float* __restrict__ kvr) {
  int bh = blockIdx.x;
  for (int i = threadIdx.x; i < 1188; i += 256) {
    float s = 0.f;
#pragma unroll
    for (int c = 0; c < NCH; ++c) s += kvp[(size_t)(bh * NCH + c) * 1188 + i];
    kvr[(size_t)bh * 1188 + i] = s;
  }
}

// ---------------- merged: banded attention (balanced split) + lin kv partials ----
// win items per bh: 3*NT2.  wi<2*NT2: qt=NT2-1-(wi>>2), part=wi&3, zp=4 (long qts)
//                           else    : qt=NT2/2-1-((wi-2*NT2)>>1), part=(wi-2*NT2)&1, zp=2
__global__ __launch_bounds__(256) void win_kv(const ushort* __restrict__ qwb,
                                              const ushort* __restrict__ kwb,
                                              const ushort* __restrict__ vwbT,
                                              ushort* __restrict__ Opart,
                                              const float* __restrict__ qk,
                                              const float* __restrict__ v_lin,
                                              float* __restrict__ kvp,
                                              int B, int S, int NT2) {
  __shared__ ushort KsS[64 * 40];      // 5120 B  (linkv: kraw floats 4352 B)
  __shared__ ushort VtS[40 * 72];      // 5760 B
  __shared__ ushort PsS[4 * 32 * 40];  // 10240 B (linkv: vsh floats 9216 B)
  const int tid = threadIdx.x;
  const int NWINBLK = NT2 * 32 * 3;
  const int bx = blockIdx.x;

  if (bx < NWINBLK) {
    // ========== banded attention; bh = bx&31 -> XCD gets 4 fixed bh ==========
    const int bh = bx & 31;
    const int wi = bx >> 5;
    int qt, part, zp;
    if (wi < 2 * NT2) { qt = NT2 - 1 - (wi >> 2); part = wi & 3; zp = 4; }
    else { int j = wi - 2 * NT2; qt = NT2 / 2 - 1 - (j >> 1); part = j & 1; zp = 2; }
    const int NT = NT2 * 2;
    const int T = min(NT, 2 * qt + 3);
    if (part >= T) return;
    const int n0 = qt * 128;
    const int lane = tid & 63, w = tid >> 6;
    const int lo = lane & 15, hi = lane >> 4;
    const short8 zv = {0, 0, 0, 0, 0, 0, 0, 0};

    short8 qf[2][2];
#pragma unroll
    for (int qr = 0; qr < 2; ++qr) {
      const ushort* qrow = qwb + ((size_t)bh * S + n0 + w * 32 + qr * 16 + lo) * 40;
      qf[qr][0] = *(const short8*)&qrow[8 * hi];
      qf[qr][1] = (hi == 0) ? *(const short8*)&qrow[32] : zv;
    }

    const ushort* kb = kwb + (size_t)bh * S * 40;
    const ushort* vb = vwbT + (size_t)bh * 40 * S;
    int evc[3];
#pragma unroll
    for (int eb = 0; eb < 3; ++eb) {
      int e = 16 * eb + lo;
      evc[eb] = (e > 39) ? 39 : e;
    }

    // staging geometry: K 320 short8, V 320 short8 across 256 threads
    const int kr0_row = tid / 5, kr0_cc = tid % 5;
    const bool p1v = (tid < 64);
    const int kr1_row = (tid + 256) / 5, kr1_cc = (tid + 256) % 5;
    const int vr0_e = tid >> 3, vr0_cc = tid & 7;
    const int vr1_e = (tid + 256) >> 3, vr1_cc = (tid + 256) & 7;
    short8 kreg[2], vreg[2];

#define ISSUE(tt) {                                                                   \
      int m0_ = (tt) * 64;                                                            \
      kreg[0] = *(const short8*)&kb[(size_t)(m0_ + kr0_row) * 40 + kr0_cc * 8];       \
      if (p1v) kreg[1] = *(const short8*)&kb[(size_t)(m0_ + kr1_row) * 40 + kr1_cc * 8]; \
      vreg[0] = *(const short8*)&vb[(size_t)vr0_e * S + m0_ + vr0_cc * 8];            \
      if (p1v) vreg[1] = *(const short8*)&vb[(size_t)vr1_e * S + m0_ + vr1_cc * 8]; }

    f32x4 Oacc[2][3];
#pragma unroll
    for (int qr = 0; qr < 2; ++qr)
#pragma unroll
      for (int eb = 0; eb < 3; ++eb) Oacc[qr][eb] = (f32x4){0.f, 0.f, 0.f, 0.f};

    ISSUE(part);

    for (int t = part; t < T; t += zp) {
      __syncthreads();            // prior tile's LDS reads complete
      *(short8*)&KsS[kr0_row * 40 + kr0_cc * 8] = kreg[0];
      if (p1v) *(short8*)&KsS[kr1_row * 40 + kr1_cc * 8] = kreg[1];
      *(short8*)&VtS[vr0_e * 72 + vr0_cc * 8] = vreg[0];
      if (p1v) *(short8*)&VtS[vr1_e * 72 + vr1_cc * 8] = vreg[1];
      __syncthreads();
      if (t + zp < T) ISSUE(t + zp);

      const int m0 = t * 64;

      // QK^T from LDS (one shared copy for all 4 waves)
      f32x4 accS[2][4];
#pragma unroll
      for (int qr = 0; qr < 2; ++qr)
#pragma unroll
        for (int bb = 0; bb < 4; ++bb) accS[qr][bb] = (f32x4){0.f, 0.f, 0.f, 0.f};
#pragma unroll
      for (int bb = 0; bb < 4; ++bb) {
        short8 kf0 = *(const short8*)&KsS[(16 * bb + lo) * 40 + 8 * hi];
        short8 kf1 = *(const short8*)&KsS[(16 * bb + lo) * 40 + 32];
#pragma unroll
        for (int qr = 0; qr < 2; ++qr) {
          accS[qr][bb] = __builtin_amdgcn_mfma_f32_16x16x32_bf16(qf[qr][0], kf0, accS[qr][bb], 0, 0, 0);
          accS[qr][bb] = __builtin_amdgcn_mfma_f32_16x16x32_bf16(qf[qr][1], kf1, accS[qr][bb], 0, 0, 0);
        }
      }

      const bool boundary = (m0 > n0);
      const int dmn = m0 - n0;
#pragma unroll
      for (int qr = 0; qr < 2; ++qr)
#pragma unroll
        for (int bb = 0; bb < 4; ++bb)
#pragma unroll
          for (int r = 0; r < 4; ++r) {
            float p = exp2f(accS[qr][bb][r]);
            if (boundary) {
              int rr = w * 32 + qr * 16 + 4 * hi + r;
              int c = 16 * bb + lo;
              if (c > rr + 63 - dmn) p = 0.f;
            }
            PsS[(w * 32 + qr * 16 + 4 * hi + r) * 40 + 16 * bb + lo] = f2bf_tr(p);
          }

      // PV (per-wave Ps region; DS ops in-order within wave)
#pragma unroll
      for (int qr = 0; qr < 2; ++qr) {
        short8 pf0 = *(const short8*)&PsS[(w * 32 + qr * 16 + lo) * 40 + 8 * hi];
        short8 pf1 = *(const short8*)&PsS[(w * 32 + qr * 16 + lo) * 40 + 32];
#pragma unroll
        for (int eb = 0; eb < 3; ++eb) {
          short8 vf0 = *(const short8*)&VtS[evc[eb] * 72 + 8 * hi];
          short8 vf1 = *(const short8*)&VtS[evc[eb] * 72 + 32 + 8 * hi];
          Oacc[qr][eb] = __builtin_amdgcn_mfma_f32_16x16x32_bf16(pf0, vf0, Oacc[qr][eb], 0, 0, 0);
          Oacc[qr][eb] = __builtin_amdgcn_mfma_f32_16x16x32_bf16(pf1, vf1, Oacc[qr][eb], 0, 0, 0);
        }
      }
    }
#undef ISSUE

    const size_t ob = ((size_t)(bh * NT2 + qt) * OPSLOTS + part) * OPS;
#pragma unroll
    for (int qr = 0; qr < 2; ++qr)
#pragma unroll
      for (int eb = 0; eb < 3; ++eb) {
        int e = 16 * eb + lo;
        if (e < 34) {
#pragma unroll
          for (int r = 0; r < 4; ++r)
            Opart[ob + (size_t)(w * 32 + qr * 16 + 4 * hi + r) * 34 + e] = f2bf(Oacc[qr][eb][r]);
        }
      }
  } else {
    // ========== linear-attention kv partials ==========
    const int idx = bx - NWINBLK;
    const int bh = idx & 31, chunk = idx >> 5;
    const int b = bh >> 4, h = bh & 15;
    float* kraw = (float*)KsS;                   // [64][17]
    float* vsh = (float*)PsS;                    // [64][36]
    if (tid < 64) { vsh[tid * 36 + 33] = 1.f; vsh[tid * 36 + 34] = 0.f; vsh[tid * 36 + 35] = 0.f; }
    f32x4 acc0 = {0.f, 0.f, 0.f, 0.f}, acc1 = {0.f, 0.f, 0.f, 0.f};
    const int d0 = tid / 9, c40 = (tid % 9) * 4;
    const int idx1 = tid + 256;
    const int d1 = idx1 / 9, c41 = (idx1 % 9) * 4;
    const int SC = S / NCH;
    const int nbeg = chunk * SC;
    __syncthreads();
    for (int n0 = nbeg; n0 < nbeg + SC; n0 += 64) {
      {
        int row = tid >> 2, f4 = (tid & 3) * 4;
        float4 kv4 = *(const float4*)&qk[(size_t)(b * S + n0 + row) * 512 + 256 + h * 16 + f4];
        kraw[row * 17 + f4 + 0] = kv4.x; kraw[row * 17 + f4 + 1] = kv4.y;
        kraw[row * 17 + f4 + 2] = kv4.z; kraw[row * 17 + f4 + 3] = kv4.w;
      }
      for (int i = tid; i < 64 * 33; i += 256) {
        int n = i / 33, e = i - n * 33;
        vsh[n * 36 + e] = v_lin[(size_t)(b * S + n0 + n) * DM + h * HD + e];
      }
      __syncthreads();
#pragma unroll 4
      for (int n = 0; n < 64; ++n) {
        {
          float ke;
          if (d0 == 0) ke = 1.f;
          else if (d0 < 17) ke = kraw[n * 17 + d0 - 1];
          else { float kk = kraw[n * 17 + d0 - 17]; ke = 0.5f * kk * kk; }
          f32x4 v = *(const f32x4*)&vsh[n * 36 + c40];
          acc0 += ke * v;
        }
        if (idx1 < 297) {
          float ke;
          if (d1 < 17) ke = kraw[n * 17 + d1 - 1];
          else { float kk = kraw[n * 17 + d1 - 17]; ke = 0.5f * kk * kk; }
          f32x4 v = *(const f32x4*)&vsh[n * 36 + c41];
          acc1 += ke * v;
        }
      }
      __syncthreads();
    }
    float* dst = kvp + (size_t)(bh * NCH + chunk) * 1188;
    *(f32x4*)&dst[d0 * 36 + c40] = acc0;
    if (idx1 < 297) *(f32x4*)&dst[d1 * 36 + c41] = acc1;
  }
}

// ---------------- merged: combine partials + linear output -> cat ----------------
__global__ __launch_bounds__(256) void comb_lin(const ushort* __restrict__ Opart,
                                                const float* __restrict__ qk,
                                                const float* __restrict__ kvr,
                                                const int* __restrict__ mask,
                                                ushort* __restrict__ cat,
                                                int B, int S, int NT2) {
  __shared__ float shf[160];
  const int tid = threadIdx.x;
  const int NCOMB = NT2 * 32;
  const int bx = blockIdx.x;

  if (bx < NCOMB) {
    const int bh = bx & 31;
    const int qt = bx >> 5;
    const int b = bh >> 4, h = bh & 15;
    const int T = min(NT2 * 2, 2 * qt + 3);
    const int P = (qt >= NT2 / 2) ? min(4, T) : min(2, T);
    const size_t base = (size_t)(bh * NT2 + qt) * OPSLOTS * OPS;
    float* linv = shf;
    if (tid < 128) {
      float l = 0.f;
      for (int p = 0; p < P; ++p) l += bf2f(Opart[base + (size_t)p * OPS + tid * 34 + 33]);
      linv[tid] = (l > 0.f) ? 1.f / l : 0.f;
    }
    __syncthreads();
    for (int i = tid; i < 128 * 33; i += 256) {
      int row = i / 33, e = i - row * 33;
      float o = 0.f;
      for (int p = 0; p < P; ++p) o += bf2f(Opart[base + (size_t)p * OPS + row * 34 + e]);
      int n = qt * 128 + row;
      cat[((size_t)(b * S + n)) * KOUT + DM + h * HD + e] = f2bf(o * linv[row]);
    }
  } else {
    const int bs = bx - NCOMB;
    const int b = (bs >= S) ? 1 : 0;
    __shared__ float qsh2[NH * 17];
    float* qsh = qsh2;
    for (int i = tid; i < NH * FEAT; i += 256)
      qsh[(i >> 4) * 17 + (i & 15)] = qk[(size_t)bs * 512 + i];
    __syncthreads();
    const int msk = mask[bs];
    for (int o = tid; o < DM; o += 256) {
      uint h = ((uint)o * 993u) >> 15;
      int e = o - (int)h * 33;
      const float* kvh = kvr + (size_t)(b * NH + (int)h) * 1188;
      float qsum = 1.f, qkv = kvh[e];
#pragma unroll
      for (int f = 0; f < FEAT; ++f) {
        float q = qsh[h * 17 + f];
        float q2 = 0.5f * q * q;
        qsum += q + q2;
        qkv += q * kvh[(1 + f) * 36 + e] + q2 * kvh[(17 + f) * 36 + e];
      }
      float z = qsum * kvh[e * 36 + 33];
      float outv = qkv / (z + EPSF);
      if (msk == 0) outv = 0.f;
      cat[(size_t)bs * KOUT + o] = f2bf(outv);
    }
  }
}

extern "C" void kernel_launch(void* const* d_in, const int* in_sizes, int n_in,
                              void* d_out, int out_size, void* d_ws, size_t ws_size,
                              hipStream_t stream) {
  const float* x      = (const float*)d_in[0];
  const int*   mask   = (const int*)d_in[1];
  const float* Wq_lin = (const float*)d_in[2];
  const float* Wk_lin = (const float*)d_in[3];
  const float* Wv_lin = (const float*)d_in[4];
  const float* Wo_lin = (const float*)d_in[5];
  const float* Wq_win = (const float*)d_in[6];
  const float* Wk_win = (const float*)d_in[7];
  const float* Wv_win = (const float*)d_in[8];
  const float* Wo_win = (const float*)d_in[9];
  float* out = (float*)d_out;

  const int BS = in_sizes[1];
  const int B = 2;
  const int S = BS / B;
  const int NT2 = S / 128;
  const int M = BS;

  // fp32 workspace
  float* ws = (float*)d_ws;
  float* qk      = ws;  ws += (size_t)BS * 512;
  float* v_lin   = ws;  ws += (size_t)BS * DM;
  float* kvp     = ws;  ws += (size_t)B * NH * NCH * 1188;
  float* kvr     = ws;  ws += (size_t)B * NH * 1188;
  // bf16 workspace
  ushort* ub     = (ushort*)ws;
  ushort* x_hi   = ub;  ub += (size_t)M * KP;
  ushort* x_lo   = ub;  ub += (size_t)M * KP;
  ushort* qkvw   = ub;  ub += (size_t)3 * 32 * S * 40;    // q | k | vT contiguous
  ushort* cat    = ub;  ub += (size_t)M * KOUT;
  ushort* WprojT = ub;  ub += (size_t)NPROJ * KP;
  ushort* WoT2   = ub;  ub += (size_t)DM * KOUT;
  ushort* Wqks   = ub;  ub += (size_t)512 * KSPLIT;
  ushort* Opart  = ub;  ub += (size_t)32 * NT2 * OPSLOTS * OPS;

  ushort* qwb  = qkvw;
  ushort* kwb  = qkvw + (size_t)32 * S * 40;
  ushort* vwbT = qkvw + (size_t)64 * S * 40;

  dim3 blk(256);

  prep_all<<<2048, blk, 0, stream>>>(x, Wq_lin, Wk_lin, Wv_lin, Wo_lin,
                                     Wq_win, Wk_win, Wv_win, Wo_win,
                                     x_hi, x_lo, Wqks, WprojT, WoT2, qk, M);

  // merged: win/linv projection (y<17) + lin q/k split GEMM by K-segment (y 17..28)
  proj_fused<<<dim3(M / 128, 29), blk, 0, stream>>>(x_hi, x_lo, Wqks, WprojT,
                                                    qk, qkvw, v_lin, mask, S);

  // merged: banded attention (XCD-pinned, balanced variable split) + lin kv partials
  win_kv<<<dim3(NT2 * 32 * 3 + B * NH * NCH), blk, 0, stream>>>(
      qwb, kwb, vwbT, Opart, qk, v_lin, kvp, B, S, NT2);

  lin_red<<<dim3(B * NH), blk, 0, stream>>>(kvp, kvr);

  // merged: combine + lin output
  comb_lin<<<dim3(NT2 * 32 + BS), blk, 0, stream>>>(Opart, qk, kvr, mask, cat, B, S, NT2);

  gemm_out<<<dim3(M / 64, (DM + 127) / 128), blk, 0, stream>>>(cat, WoT2, out, S);
}

// Round 18
// 178.755 us; speedup vs baseline: 1.0235x; 1.0235x over previous
//
#include <hip/hip_runtime.h>

#define NH 16
#define FEAT 16
#define HD 33
#define DM 528
#define WIN 64
#define EPSF 1e-9f
#define K1C (0.17407765595569785f * 1.4426950408889634f)
#define KP 544               // padded K for projections
#define KSPLIT 1632          // 3*544 for hi/lo split GEMM
#define NPROJ 2112           // 528 win-q + 528 win-k + 528 win-v + 528 lin-v
#define KOUT 1056            // 528 lin + 528 win
#define OPS 4352             // Opart per-part stride (128 rows x 34)
#define NCH 16               // lin_kv chunks
#define ZPARTS 2             // win split-K parts (strided)

typedef float f32x4 __attribute__((ext_vector_type(4)));
typedef short short8 __attribute__((ext_vector_type(8)));

__device__ inline ushort f2bf(float f) {
  uint u = __float_as_uint(f);
  uint r = u + 0x7fffu + ((u >> 16) & 1u);
  return (ushort)(r >> 16);
}
__device__ inline ushort f2bf_tr(float f) { return (ushort)(__float_as_uint(f) >> 16); }
__device__ inline float bf2f(ushort u) { return __uint_as_float(((uint)u) << 16); }

// ---------------- fused prep ------------------------------------------------------
// blocks [0,1024):   x -> bf16 hi/lo (padded) + qk zero   (grid-stride)
// blocks [1024,...): one 64x64 LDS-transpose tile of a weight pack each
//   tiles 0..215   : Wqks  (3 segs x 9 ktiles x 8 ntiles)
//   tiles 216..512 : WprojT (9 ktiles x 33 ntiles)
//   tiles 513..665 : WoT2  (17 ktiles x 9 ntiles)
__global__ __launch_bounds__(256) void prep_all(const float* __restrict__ x,
                                                const float* __restrict__ Wq_lin,
                                                const float* __restrict__ Wk_lin,
                                                const float* __restrict__ Wv_lin,
                                                const float* __restrict__ Wo_lin,
                                                const float* __restrict__ Wq_win,
                                                const float* __restrict__ Wk_win,
                                                const float* __restrict__ Wv_win,
                                                const float* __restrict__ Wo_win,
                                                ushort* __restrict__ xhi,
                                                ushort* __restrict__ xlo,
                                                ushort* __restrict__ Wqks,
                                                ushort* __restrict__ WprojT,
                                                ushort* __restrict__ WoT2,
                                                float* __restrict__ qk, int M) {
  const int tid = threadIdx.x;
  if (blockIdx.x < 1024) {
    const int stride = 1024 * 256;
    const int tid0 = blockIdx.x * 256 + tid;
    for (int j = tid0; j < M * 68; j += stride) {
      int row = j / 68, c8 = (j - row * 68) * 8;
      short8 h8, l8;
      if (c8 < DM) {
        float4 f0 = *(const float4*)&x[(size_t)row * DM + c8];
        float4 f1 = *(const float4*)&x[(size_t)row * DM + c8 + 4];
        float vv[8] = {f0.x, f0.y, f0.z, f0.w, f1.x, f1.y, f1.z, f1.w};
#pragma unroll
        for (int z = 0; z < 8; ++z) {
          ushort h = f2bf(vv[z]);
          h8[z] = (short)h;
          l8[z] = (short)f2bf(vv[z] - bf2f(h));
        }
      } else {
        h8 = (short8){0, 0, 0, 0, 0, 0, 0, 0};
        l8 = h8;
      }
      *(short8*)&xhi[(size_t)row * KP + c8] = h8;
      *(short8*)&xlo[(size_t)row * KP + c8] = l8;
    }
    for (int i = tid0; i < M * 128; i += stride)
      ((float4*)qk)[i] = make_float4(0.f, 0.f, 0.f, 0.f);
    return;
  }

  // ---- weight transpose tiles ----
  const int id = blockIdx.x - 1024;
  if (id >= 666) return;
  __shared__ float t[64][65];
  const int tx = tid & 63, ty = tid >> 6;

  if (id < 216) {
    // Wqks: dst [512][1632], seg k-offset seg*KP; src [k<528][n<512] = Wq|Wk
    const int seg = id / 72;
    const int rem = id - seg * 72;
    const int k0 = (rem >> 3) * 64;      // 0..512
    const int n0 = (rem & 7) * 64;
    for (int rr = ty; rr < 64; rr += 4) {
      int kk = k0 + rr, n = n0 + tx;
      float v = 0.f;
      if (kk < DM) v = (n < 256) ? Wq_lin[(size_t)kk * 256 + n]
                                 : Wk_lin[(size_t)kk * 256 + (n - 256)];
      t[rr][tx] = v;
    }
    __syncthreads();
    for (int cc = ty; cc < 64; cc += 4) {
      int n = n0 + cc, kk = k0 + tx;
      if (kk < KP) {
        float v = t[tx][cc];
        ushort h = f2bf(v);
        if (seg == 2) h = f2bf(v - bf2f(h));
        Wqks[(size_t)n * KSPLIT + seg * KP + kk] = h;
      }
    }
  } else if (id < 513) {
    // WprojT: dst [2112][544]; src [k<528][n<2112] = Wq_win|Wk_win*K1C|Wv_win|Wv_lin
    const int rem = id - 216;
    const int kt = rem / 33, nt = rem - kt * 33;
    const int k0 = kt * 64, n0 = nt * 64;
    for (int rr = ty; rr < 64; rr += 4) {
      int kk = k0 + rr, n = n0 + tx;
      float v = 0.f;
      if (kk < DM) {
        if (n < DM) v = Wq_win[(size_t)kk * DM + n];
        else if (n < 2 * DM) v = Wk_win[(size_t)kk * DM + (n - DM)] * K1C;
        else if (n < 3 * DM) v = Wv_win[(size_t)kk * DM + (n - 2 * DM)];
        else v = Wv_lin[(size_t)kk * DM + (n - 3 * DM)];
      }
      t[rr][tx] = v;
    }
    __syncthreads();
    for (int cc = ty; cc < 64; cc += 4) {
      int n = n0 + cc, kk = k0 + tx;
      if (kk < KP) WprojT[(size_t)n * KP + kk] = f2bf(t[tx][cc]);
    }
  } else {
    // WoT2: dst [528][1056]; src k<528: Wo_lin, else Wo_win
    const int rem = id - 513;
    const int kt = rem / 9, nt = rem - kt * 9;
    const int k0 = kt * 64, n0 = nt * 64;
    for (int rr = ty; rr < 64; rr += 4) {
      int kk = k0 + rr, n = n0 + tx;
      float v = 0.f;
      if (n < DM && kk < KOUT)
        v = (kk < DM) ? Wo_lin[(size_t)kk * DM + n] : Wo_win[(size_t)(kk - DM) * DM + n];
      t[rr][tx] = v;
    }
    __syncthreads();
    for (int cc = ty; cc < 64; cc += 4) {
      int n = n0 + cc, kk = k0 + tx;
      if (n < DM && kk < KOUT) WoT2[(size_t)n * KOUT + kk] = f2bf(t[tx][cc]);
    }
  }
}

// ---------------- merged projection GEMMs (one launch) ---------------------------
// y < 17 : win q/k/v + lin v projection;  y in 17..28: lin q/k split, one K-segment
__global__ __launch_bounds__(256) void proj_fused(const ushort* __restrict__ xhi,
                                                  const ushort* __restrict__ xlo,
                                                  const ushort* __restrict__ Wqks,
                                                  const ushort* __restrict__ WprojT,
                                                  float* __restrict__ qk,
                                                  ushort* __restrict__ qkvw,
                                                  float* __restrict__ v_lin,
                                                  const int* __restrict__ maskp,
                                                  int S) {
  __shared__ ushort As[128][36];
  __shared__ ushort Bs[128][36];
  const int bm = blockIdx.x * 128;
  const int tid = threadIdx.x;
  const int lane = tid & 63, w = tid >> 6;
  const int lo = lane & 15, hi = lane >> 4;
  const int wr = w >> 1, wc = w & 1;
  const short8 zv = {0, 0, 0, 0, 0, 0, 0, 0};
  f32x4 acc[4][4];
#pragma unroll
  for (int mb = 0; mb < 4; ++mb)
#pragma unroll
    for (int nb = 0; nb < 4; ++nb) acc[mb][nb] = (f32x4){0.f, 0.f, 0.f, 0.f};

  if (blockIdx.y < 17) {
    const int bn = blockIdx.y * 128;
    for (int k0 = 0; k0 < KP; k0 += 32) {
      short8 a_ld[2], b_ld[2];
#pragma unroll
      for (int p = 0; p < 2; ++p) {
        int c = tid + p * 256;
        int row = c >> 2, cc = c & 3;
        a_ld[p] = *(const short8*)&xhi[(size_t)(bm + row) * KP + k0 + cc * 8];
        int bnr = bn + row;
        b_ld[p] = (bnr < NPROJ) ? *(const short8*)&WprojT[(size_t)bnr * KP + k0 + cc * 8] : zv;
      }
      __syncthreads();
#pragma unroll
      for (int p = 0; p < 2; ++p) {
        int c = tid + p * 256;
        int row = c >> 2, cc = c & 3;
        *(short8*)&As[row][cc * 8] = a_ld[p];
        *(short8*)&Bs[row][cc * 8] = b_ld[p];
      }
      __syncthreads();
      short8 afr[4], bfr[4];
#pragma unroll
      for (int mb = 0; mb < 4; ++mb) afr[mb] = *(const short8*)&As[wr * 64 + 16 * mb + lo][8 * hi];
#pragma unroll
      for (int nb = 0; nb < 4; ++nb) bfr[nb] = *(const short8*)&Bs[wc * 64 + 16 * nb + lo][8 * hi];
#pragma unroll
      for (int mb = 0; mb < 4; ++mb)
#pragma unroll
        for (int nb = 0; nb < 4; ++nb)
          acc[mb][nb] = __builtin_amdgcn_mfma_f32_16x16x32_bf16(afr[mb], bfr[nb], acc[mb][nb], 0, 0, 0);
    }
#pragma unroll
    for (int nb = 0; nb < 4; ++nb) {
      const int col = bn + wc * 64 + 16 * nb + lo;
      if (col >= NPROJ) continue;
      const int seg = col / DM;          // 0=win q 1=win k 2=win v 3=lin v
      const int cc = col - seg * DM;
      if (seg == 3) {
#pragma unroll
        for (int mb = 0; mb < 4; ++mb)
#pragma unroll
          for (int r = 0; r < 4; ++r) {
            int row = bm + wr * 64 + 16 * mb + 4 * hi + r;
            v_lin[(size_t)row * DM + cc] = acc[mb][nb][r];
          }
      } else {
        const uint h = ((uint)cc * 993u) >> 15;
        const int e = cc - (int)h * 33;
        ushort* dst = qkvw + (size_t)seg * (32u * (uint)S * 40u);
#pragma unroll
        for (int mb = 0; mb < 4; ++mb)
#pragma unroll
          for (int r = 0; r < 4; ++r) {
            int row = bm + wr * 64 + 16 * mb + 4 * hi + r;
            int b = (row >= S) ? 1 : 0;
            int nn = row - b * S;
            float val = acc[mb][nb][r];
            if (seg == 2) {
              size_t tb = (size_t)(b * NH + (int)h) * 40;
              dst[(tb + e) * S + nn] = f2bf(val);
              if (e == 0) {
                dst[(tb + 33) * S + nn] = 0x3F80;
#pragma unroll
                for (int z = 34; z < 40; ++z) dst[(tb + z) * S + nn] = 0;
              }
            } else {
              size_t base = ((size_t)(b * NH + (int)h) * S + nn) * 40;
              dst[base + e] = f2bf(val);
              if (e == 0) {
                ushort pad33 = (seg == 0) ? (ushort)0x3F80
                                          : (maskp[row] ? (ushort)0 : f2bf(-1e30f));
                dst[base + 33] = pad33;
#pragma unroll
                for (int z = 34; z < 40; ++z) dst[base + z] = 0;
              }
            }
          }
      }
    }
  } else {
    const int yy = blockIdx.y - 17;      // 0..11
    const int seg = yy >> 2;             // K-segment 0..2
    const int bn = (yy & 3) * 128;
    const ushort* xsrc = (seg == 1) ? xlo : xhi;
    const int kb = seg * KP;
    for (int k0 = 0; k0 < KP; k0 += 32) {
      short8 a_ld[2], b_ld[2];
#pragma unroll
      for (int p = 0; p < 2; ++p) {
        int c = tid + p * 256;
        int row = c >> 2, cc = c & 3;
        a_ld[p] = *(const short8*)&xsrc[(size_t)(bm + row) * KP + k0 + cc * 8];
        b_ld[p] = *(const short8*)&Wqks[(size_t)(bn + row) * KSPLIT + kb + k0 + cc * 8];
      }
      __syncthreads();
#pragma unroll
      for (int p = 0; p < 2; ++p) {
        int c = tid + p * 256;
        int row = c >> 2, cc = c & 3;
        *(short8*)&As[row][cc * 8] = a_ld[p];
        *(short8*)&Bs[row][cc * 8] = b_ld[p];
      }
      __syncthreads();
      short8 afr[4], bfr[4];
#pragma unroll
      for (int mb = 0; mb < 4; ++mb) afr[mb] = *(const short8*)&As[wr * 64 + 16 * mb + lo][8 * hi];
#pragma unroll
      for (int nb = 0; nb < 4; ++nb) bfr[nb] = *(const short8*)&Bs[wc * 64 + 16 * nb + lo][8 * hi];
#pragma unroll
      for (int mb = 0; mb < 4; ++mb)
#pragma unroll
        for (int nb = 0; nb < 4; ++nb)
          acc[mb][nb] = __builtin_amdgcn_mfma_f32_16x16x32_bf16(afr[mb], bfr[nb], acc[mb][nb], 0, 0, 0);
    }
#pragma unroll
    for (int mb = 0; mb < 4; ++mb)
#pragma unroll
      for (int nb = 0; nb < 4; ++nb) {
        int col = bn + wc * 64 + 16 * nb + lo;
#pragma unroll
        for (int r = 0; r < 4; ++r) {
          int row = bm + wr * 64 + 16 * mb + 4 * hi + r;
          atomicAdd(&qk[(size_t)row * 512 + col], acc[mb][nb][r]);
        }
      }
  }
}

// ---------------- final output GEMM: BM=64 x BN=128 ------------------------------
__global__ __launch_bounds__(256) void gemm_out(const ushort* __restrict__ A,
                                                const ushort* __restrict__ Bt,
                                                float* __restrict__ C, int S) {
  __shared__ ushort As[64][36];
  __shared__ ushort Bs[128][36];
  const int bm = blockIdx.x * 64, bn = blockIdx.y * 128;
  const int tid = threadIdx.x;
  const int lane = tid & 63, w = tid >> 6;
  const int lo = lane & 15, hi = lane >> 4;
  const int wr = w & 1, wc = w >> 1;
  f32x4 acc[2][4];
#pragma unroll
  for (int mb = 0; mb < 2; ++mb)
#pragma unroll
    for (int nb = 0; nb < 4; ++nb) acc[mb][nb] = (f32x4){0.f, 0.f, 0.f, 0.f};
  const short8 zv = {0, 0, 0, 0, 0, 0, 0, 0};

  for (int k0 = 0; k0 < KOUT; k0 += 32) {
    short8 a_ld, b_ld[2];
    {
      int row = tid >> 2, cc = tid & 3;
      a_ld = *(const short8*)&A[(size_t)(bm + row) * KOUT + k0 + cc * 8];
    }
#pragma unroll
    for (int p = 0; p < 2; ++p) {
      int c = tid + p * 256;
      int row = c >> 2, cc = c & 3;
      int bnr = bn + row;
      b_ld[p] = (bnr < DM) ? *(const short8*)&Bt[(size_t)bnr * KOUT + k0 + cc * 8] : zv;
    }
    __syncthreads();
    {
      int row = tid >> 2, cc = tid & 3;
      *(short8*)&As[row][cc * 8] = a_ld;
    }
#pragma unroll
    for (int p = 0; p < 2; ++p) {
      int c = tid + p * 256;
      int row = c >> 2, cc = c & 3;
      *(short8*)&Bs[row][cc * 8] = b_ld[p];
    }
    __syncthreads();
    short8 afr[2], bfr[4];
#pragma unroll
    for (int mb = 0; mb < 2; ++mb) afr[mb] = *(const short8*)&As[wr * 32 + 16 * mb + lo][8 * hi];
#pragma unroll
    for (int nb = 0; nb < 4; ++nb) bfr[nb] = *(const short8*)&Bs[wc * 64 + 16 * nb + lo][8 * hi];
#pragma unroll
    for (int mb = 0; mb < 2; ++mb)
#pragma unroll
      for (int nb = 0; nb < 4; ++nb)
        acc[mb][nb] = __builtin_amdgcn_mfma_f32_16x16x32_bf16(afr[mb], bfr[nb], acc[mb][nb], 0, 0, 0);
  }
#pragma unroll
  for (int nb = 0; nb < 4; ++nb) {
    const int col = bn + wc * 64 + 16 * nb + lo;
    if (col >= DM) continue;
#pragma unroll
    for (int mb = 0; mb < 2; ++mb)
#pragma unroll
      for (int r = 0; r < 4; ++r) {
        int row = bm + wr * 32 + 16 * mb + 4 * hi + r;
        C[(size_t)row * DM + col] = acc[mb][nb][r];
      }
  }
}

__global__ __launch_bounds__(256) void lin_red(const float* __restrict__ kvp,
                                               float* __restrict__ kvr) {
  int bh = blockIdx.x;
  for (int i = threadIdx.x; i < 1188; i += 256) {
    float s = 0.f;
#pragma unroll
    for (int c = 0; c < NCH; ++c) s += kvp[(size_t)(bh * NCH + c) * 1188 + i];
    kvr[(size_t)bh * 1188 + i] = s;
  }
}

// ---------------- merged: banded attention (LDS-staged K/V) + lin kv partials ----
__global__ __launch_bounds__(256) void win_kv(const ushort* __restrict__ qwb,
                                              const ushort* __restrict__ kwb,
                                              const ushort* __restrict__ vwbT,
                                              ushort* __restrict__ Opart,
                                              const float* __restrict__ qk,
                                              const float* __restrict__ v_lin,
                                              float* __restrict__ kvp,
                                              int B, int S, int NT2) {
  __shared__ ushort KsS[64 * 40];      // 5120 B  (linkv: kraw floats 4352 B)
  __shared__ ushort VtS[40 * 72];      // 5760 B
  __shared__ ushort PsS[4 * 32 * 40];  // 10240 B (linkv: vsh floats 9216 B)
  const int tid = threadIdx.x;
  const int NWINBLK = NT2 * 32 * ZPARTS;
  const int bx = blockIdx.x;

  if (bx < NWINBLK) {
    // ========== banded attention; bh = bx&31 -> XCD gets 4 fixed bh ==========
    const int bh = bx & 31;
    const int qp = bx >> 5;
    const int part = qp / NT2;
    const int qt = NT2 - 1 - (qp - part * NT2);   // longest first
    const int NT = NT2 * 2;
    const int T = min(NT, 2 * qt + 3);
    if (part >= T) return;
    const int n0 = qt * 128;
    const int lane = tid & 63, w = tid >> 6;
    const int lo = lane & 15, hi = lane >> 4;
    const short8 zv = {0, 0, 0, 0, 0, 0, 0, 0};

    short8 qf[2][2];
#pragma unroll
    for (int qr = 0; qr < 2; ++qr) {
      const ushort* qrow = qwb + ((size_t)bh * S + n0 + w * 32 + qr * 16 + lo) * 40;
      qf[qr][0] = *(const short8*)&qrow[8 * hi];
      qf[qr][1] = (hi == 0) ? *(const short8*)&qrow[32] : zv;
    }

    const ushort* kb = kwb + (size_t)bh * S * 40;
    const ushort* vb = vwbT + (size_t)bh * 40 * S;
    int evc[3];
#pragma unroll
    for (int eb = 0; eb < 3; ++eb) {
      int e = 16 * eb + lo;
      evc[eb] = (e > 39) ? 39 : e;
    }

    // staging geometry: K 320 short8, V 320 short8 across 256 threads
    const int kr0_row = tid / 5, kr0_cc = tid % 5;
    const bool p1v = (tid < 64);
    const int kr1_row = (tid + 256) / 5, kr1_cc = (tid + 256) % 5;
    const int vr0_e = tid >> 3, vr0_cc = tid & 7;
    const int vr1_e = (tid + 256) >> 3, vr1_cc = (tid + 256) & 7;
    short8 kreg[2], vreg[2];

#define ISSUE(tt) {                                                                   \
      int m0_ = (tt) * 64;                                                            \
      kreg[0] = *(const short8*)&kb[(size_t)(m0_ + kr0_row) * 40 + kr0_cc * 8];       \
      if (p1v) kreg[1] = *(const short8*)&kb[(size_t)(m0_ + kr1_row) * 40 + kr1_cc * 8]; \
      vreg[0] = *(const short8*)&vb[(size_t)vr0_e * S + m0_ + vr0_cc * 8];            \
      if (p1v) vreg[1] = *(const short8*)&vb[(size_t)vr1_e * S + m0_ + vr1_cc * 8]; }

    f32x4 Oacc[2][3];
#pragma unroll
    for (int qr = 0; qr < 2; ++qr)
#pragma unroll
      for (int eb = 0; eb < 3; ++eb) Oacc[qr][eb] = (f32x4){0.f, 0.f, 0.f, 0.f};

    ISSUE(part);

    for (int t = part; t < T; t += ZPARTS) {
      __syncthreads();            // prior tile's LDS reads complete
      *(short8*)&KsS[kr0_row * 40 + kr0_cc * 8] = kreg[0];
      if (p1v) *(short8*)&KsS[kr1_row * 40 + kr1_cc * 8] = kreg[1];
      *(short8*)&VtS[vr0_e * 72 + vr0_cc * 8] = vreg[0];
      if (p1v) *(short8*)&VtS[vr1_e * 72 + vr1_cc * 8] = vreg[1];
      __syncthreads();
      if (t + ZPARTS < T) ISSUE(t + ZPARTS);

      const int m0 = t * 64;

      // QK^T from LDS (one shared copy for all 4 waves)
      f32x4 accS[2][4];
#pragma unroll
      for (int qr = 0; qr < 2; ++qr)
#pragma unroll
        for (int bb = 0; bb < 4; ++bb) accS[qr][bb] = (f32x4){0.f, 0.f, 0.f, 0.f};
#pragma unroll
      for (int bb = 0; bb < 4; ++bb) {
        short8 kf0 = *(const short8*)&KsS[(16 * bb + lo) * 40 + 8 * hi];
        short8 kf1 = *(const short8*)&KsS[(16 * bb + lo) * 40 + 32];
#pragma unroll
        for (int qr = 0; qr < 2; ++qr) {
          accS[qr][bb] = __builtin_amdgcn_mfma_f32_16x16x32_bf16(qf[qr][0], kf0, accS[qr][bb], 0, 0, 0);
          accS[qr][bb] = __builtin_amdgcn_mfma_f32_16x16x32_bf16(qf[qr][1], kf1, accS[qr][bb], 0, 0, 0);
        }
      }

      const bool boundary = (m0 > n0);
      const int dmn = m0 - n0;
#pragma unroll
      for (int qr = 0; qr < 2; ++qr)
#pragma unroll
        for (int bb = 0; bb < 4; ++bb)
#pragma unroll
          for (int r = 0; r < 4; ++r) {
            float p = exp2f(accS[qr][bb][r]);
            if (boundary) {
              int rr = w * 32 + qr * 16 + 4 * hi + r;
              int c = 16 * bb + lo;
              if (c > rr + 63 - dmn) p = 0.f;
            }
            PsS[(w * 32 + qr * 16 + 4 * hi + r) * 40 + 16 * bb + lo] = f2bf_tr(p);
          }

      // PV (per-wave Ps region; DS ops in-order within wave)
#pragma unroll
      for (int qr = 0; qr < 2; ++qr) {
        short8 pf0 = *(const short8*)&PsS[(w * 32 + qr * 16 + lo) * 40 + 8 * hi];
        short8 pf1 = *(const short8*)&PsS[(w * 32 + qr * 16 + lo) * 40 + 32];
#pragma unroll
        for (int eb = 0; eb < 3; ++eb) {
          short8 vf0 = *(const short8*)&VtS[evc[eb] * 72 + 8 * hi];
          short8 vf1 = *(const short8*)&VtS[evc[eb] * 72 + 32 + 8 * hi];
          Oacc[qr][eb] = __builtin_amdgcn_mfma_f32_16x16x32_bf16(pf0, vf0, Oacc[qr][eb], 0, 0, 0);
          Oacc[qr][eb] = __builtin_amdgcn_mfma_f32_16x16x32_bf16(pf1, vf1, Oacc[qr][eb], 0, 0, 0);
        }
      }
    }
#undef ISSUE

    const size_t ob = ((size_t)(bh * NT2 + qt) * ZPARTS + part) * OPS;
#pragma unroll
    for (int qr = 0; qr < 2; ++qr)
#pragma unroll
      for (int eb = 0; eb < 3; ++eb) {
        int e = 16 * eb + lo;
        if (e < 34) {
#pragma unroll
          for (int r = 0; r < 4; ++r)
            Opart[ob + (size_t)(w * 32 + qr * 16 + 4 * hi + r) * 34 + e] = f2bf(Oacc[qr][eb][r]);
        }
      }
  } else {
    // ========== linear-attention kv partials ==========
    const int idx = bx - NWINBLK;
    const int bh = idx & 31, chunk = idx >> 5;
    const int b = bh >> 4, h = bh & 15;
    float* kraw = (float*)KsS;                   // [64][17]
    float* vsh = (float*)PsS;                    // [64][36]
    if (tid < 64) { vsh[tid * 36 + 33] = 1.f; vsh[tid * 36 + 34] = 0.f; vsh[tid * 36 + 35] = 0.f; }
    f32x4 acc0 = {0.f, 0.f, 0.f, 0.f}, acc1 = {0.f, 0.f, 0.f, 0.f};
    const int d0 = tid / 9, c40 = (tid % 9) * 4;
    const int idx1 = tid + 256;
    const int d1 = idx1 / 9, c41 = (idx1 % 9) * 4;
    const int SC = S / NCH;
    const int nbeg = chunk * SC;
    __syncthreads();
    for (int n0 = nbeg; n0 < nbeg + SC; n0 += 64) {
      {
        int row = tid >> 2, f4 = (tid & 3) * 4;
        float4 kv4 = *(const float4*)&qk[(size_t)(b * S + n0 + row) * 512 + 256 + h * 16 + f4];
        kraw[row * 17 + f4 + 0] = kv4.x; kraw[row * 17 + f4 + 1] = kv4.y;
        kraw[row * 17 + f4 + 2] = kv4.z; kraw[row * 17 + f4 + 3] = kv4.w;
      }
      for (int i = tid; i < 64 * 33; i += 256) {
        int n = i / 33, e = i - n * 33;
        vsh[n * 36 + e] = v_lin[(size_t)(b * S + n0 + n) * DM + h * HD + e];
      }
      __syncthreads();
#pragma unroll 4
      for (int n = 0; n < 64; ++n) {
        {
          float ke;
          if (d0 == 0) ke = 1.f;
          else if (d0 < 17) ke = kraw[n * 17 + d0 - 1];
          else { float kk = kraw[n * 17 + d0 - 17]; ke = 0.5f * kk * kk; }
          f32x4 v = *(const f32x4*)&vsh[n * 36 + c40];
          acc0 += ke * v;
        }
        if (idx1 < 297) {
          float ke;
          if (d1 < 17) ke = kraw[n * 17 + d1 - 1];
          else { float kk = kraw[n * 17 + d1 - 17]; ke = 0.5f * kk * kk; }
          f32x4 v = *(const f32x4*)&vsh[n * 36 + c41];
          acc1 += ke * v;
        }
      }
      __syncthreads();
    }
    float* dst = kvp + (size_t)(bh * NCH + chunk) * 1188;
    *(f32x4*)&dst[d0 * 36 + c40] = acc0;
    if (idx1 < 297) *(f32x4*)&dst[d1 * 36 + c41] = acc1;
  }
}

// ---------------- merged: combine partials + linear output -> cat ----------------
__global__ __launch_bounds__(256) void comb_lin(const ushort* __restrict__ Opart,
                                                const float* __restrict__ qk,
                                                const float* __restrict__ kvr,
                                                const int* __restrict__ mask,
                                                ushort* __restrict__ cat,
                                                int B, int S, int NT2) {
  __shared__ float shf[160];
  const int tid = threadIdx.x;
  const int NCOMB = NT2 * 32;
  const int bx = blockIdx.x;

  if (bx < NCOMB) {
    const int bh = bx & 31;
    const int qt = bx >> 5;
    const int b = bh >> 4, h = bh & 15;
    const int T = min(NT2 * 2, 2 * qt + 3);
    const int P = min(ZPARTS, T);
    const size_t base = (size_t)(bh * NT2 + qt) * ZPARTS * OPS;
    float* linv = shf;
    if (tid < 128) {
      float l = 0.f;
      for (int p = 0; p < P; ++p) l += bf2f(Opart[base + (size_t)p * OPS + tid * 34 + 33]);
      linv[tid] = (l > 0.f) ? 1.f / l : 0.f;
    }
    __syncthreads();
    for (int i = tid; i < 128 * 33; i += 256) {
      int row = i / 33, e = i - row * 33;
      float o = 0.f;
      for (int p = 0; p < P; ++p) o += bf2f(Opart[base + (size_t)p * OPS + row * 34 + e]);
      int n = qt * 128 + row;
      cat[((size_t)(b * S + n)) * KOUT + DM + h * HD + e] = f2bf(o * linv[row]);
    }
  } else {
    const int bs = bx - NCOMB;
    const int b = (bs >= S) ? 1 : 0;
    __shared__ float qsh2[NH * 17];
    float* qsh = qsh2;
    for (int i = tid; i < NH * FEAT; i += 256)
      qsh[(i >> 4) * 17 + (i & 15)] = qk[(size_t)bs * 512 + i];
    __syncthreads();
    const int msk = mask[bs];
    for (int o = tid; o < DM; o += 256) {
      uint h = ((uint)o * 993u) >> 15;
      int e = o - (int)h * 33;
      const float* kvh = kvr + (size_t)(b * NH + (int)h) * 1188;
      float qsum = 1.f, qkv = kvh[e];
#pragma unroll
      for (int f = 0; f < FEAT; ++f) {
        float q = qsh[h * 17 + f];
        float q2 = 0.5f * q * q;
        qsum += q + q2;
        qkv += q * kvh[(1 + f) * 36 + e] + q2 * kvh[(17 + f) * 36 + e];
      }
      float z = qsum * kvh[e * 36 + 33];
      float outv = qkv / (z + EPSF);
      if (msk == 0) outv = 0.f;
      cat[(size_t)bs * KOUT + o] = f2bf(outv);
    }
  }
}

extern "C" void kernel_launch(void* const* d_in, const int* in_sizes, int n_in,
                              void* d_out, int out_size, void* d_ws, size_t ws_size,
                              hipStream_t stream) {
  const float* x      = (const float*)d_in[0];
  const int*   mask   = (const int*)d_in[1];
  const float* Wq_lin = (const float*)d_in[2];
  const float* Wk_lin = (const float*)d_in[3];
  const float* Wv_lin = (const float*)d_in[4];
  const float* Wo_lin = (const float*)d_in[5];
  const float* Wq_win = (const float*)d_in[6];
  const float* Wk_win = (const float*)d_in[7];
  const float* Wv_win = (const float*)d_in[8];
  const float* Wo_win = (const float*)d_in[9];
  float* out = (float*)d_out;

  const int BS = in_sizes[1];
  const int B = 2;
  const int S = BS / B;
  const int NT2 = S / 128;
  const int M = BS;

  // fp32 workspace
  float* ws = (float*)d_ws;
  float* qk      = ws;  ws += (size_t)BS * 512;
  float* v_lin   = ws;  ws += (size_t)BS * DM;
  float* kvp     = ws;  ws += (size_t)B * NH * NCH * 1188;
  float* kvr     = ws;  ws += (size_t)B * NH * 1188;
  // bf16 workspace
  ushort* ub     = (ushort*)ws;
  ushort* x_hi   = ub;  ub += (size_t)M * KP;
  ushort* x_lo   = ub;  ub += (size_t)M * KP;
  ushort* qkvw   = ub;  ub += (size_t)3 * 32 * S * 40;    // q | k | vT contiguous
  ushort* cat    = ub;  ub += (size_t)M * KOUT;
  ushort* WprojT = ub;  ub += (size_t)NPROJ * KP;
  ushort* WoT2   = ub;  ub += (size_t)DM * KOUT;
  ushort* Wqks   = ub;  ub += (size_t)512 * KSPLIT;
  ushort* Opart  = ub;  ub += (size_t)32 * NT2 * ZPARTS * OPS;

  ushort* qwb  = qkvw;
  ushort* kwb  = qkvw + (size_t)32 * S * 40;
  ushort* vwbT = qkvw + (size_t)64 * S * 40;

  dim3 blk(256);

  prep_all<<<2048, blk, 0, stream>>>(x, Wq_lin, Wk_lin, Wv_lin, Wo_lin,
                                     Wq_win, Wk_win, Wv_win, Wo_win,
                                     x_hi, x_lo, Wqks, WprojT, WoT2, qk, M);

  // merged: win/linv projection (y<17) + lin q/k split GEMM by K-segment (y 17..28)
  proj_fused<<<dim3(M / 128, 29), blk, 0, stream>>>(x_hi, x_lo, Wqks, WprojT,
                                                    qk, qkvw, v_lin, mask, S);

  // merged: banded attention (XCD-pinned, LDS-staged K/V, ZPARTS=2) + lin kv partials
  win_kv<<<dim3(NT2 * 32 * ZPARTS + B * NH * NCH), blk, 0, stream>>>(
      qwb, kwb, vwbT, Opart, qk, v_lin, kvp, B, S, NT2);

  lin_red<<<dim3(B * NH), blk, 0, stream>>>(kvp, kvr);

  // merged: combine + lin output
  comb_lin<<<dim3(NT2 * 32 + BS), blk, 0, stream>>>(Opart, qk, kvr, mask, cat, B, S, NT2);

  gemm_out<<<dim3(M / 64, (DM + 127) / 128), blk, 0, stream>>>(cat, WoT2, out, S);
}

// Round 19
// 177.776 us; speedup vs baseline: 1.0292x; 1.0055x over previous
//
#include <hip/hip_runtime.h>

#define NH 16
#define FEAT 16
#define HD 33
#define DM 528
#define WIN 64
#define EPSF 1e-9f
#define K1C (0.17407765595569785f * 1.4426950408889634f)
#define KP 544               // padded K for projections
#define KSPLIT 1632          // 3*544 for hi/lo split GEMM
#define NPROJ 2112           // 528 win-q + 528 win-k + 528 win-v + 528 lin-v
#define KOUT 1056            // 528 lin + 528 win
#define OPS 4352             // Opart per-part stride (128 rows x 34)
#define NCH 16               // lin_kv chunks
#define ZPARTS 2             // win split-K parts (strided)

typedef float f32x4 __attribute__((ext_vector_type(4)));
typedef short short8 __attribute__((ext_vector_type(8)));

__device__ inline ushort f2bf(float f) {
  uint u = __float_as_uint(f);
  uint r = u + 0x7fffu + ((u >> 16) & 1u);
  return (ushort)(r >> 16);
}
__device__ inline ushort f2bf_tr(float f) { return (ushort)(__float_as_uint(f) >> 16); }
__device__ inline float bf2f(ushort u) { return __uint_as_float(((uint)u) << 16); }

// ---------------- fused prep ------------------------------------------------------
__global__ __launch_bounds__(256) void prep_all(const float* __restrict__ x,
                                                const float* __restrict__ Wq_lin,
                                                const float* __restrict__ Wk_lin,
                                                const float* __restrict__ Wv_lin,
                                                const float* __restrict__ Wo_lin,
                                                const float* __restrict__ Wq_win,
                                                const float* __restrict__ Wk_win,
                                                const float* __restrict__ Wv_win,
                                                const float* __restrict__ Wo_win,
                                                ushort* __restrict__ xhi,
                                                ushort* __restrict__ xlo,
                                                ushort* __restrict__ Wqks,
                                                ushort* __restrict__ WprojT,
                                                ushort* __restrict__ WoT2,
                                                float* __restrict__ qk, int M) {
  const int tid = threadIdx.x;
  if (blockIdx.x < 1024) {
    const int stride = 1024 * 256;
    const int tid0 = blockIdx.x * 256 + tid;
    for (int j = tid0; j < M * 68; j += stride) {
      int row = j / 68, c8 = (j - row * 68) * 8;
      short8 h8, l8;
      if (c8 < DM) {
        float4 f0 = *(const float4*)&x[(size_t)row * DM + c8];
        float4 f1 = *(const float4*)&x[(size_t)row * DM + c8 + 4];
        float vv[8] = {f0.x, f0.y, f0.z, f0.w, f1.x, f1.y, f1.z, f1.w};
#pragma unroll
        for (int z = 0; z < 8; ++z) {
          ushort h = f2bf(vv[z]);
          h8[z] = (short)h;
          l8[z] = (short)f2bf(vv[z] - bf2f(h));
        }
      } else {
        h8 = (short8){0, 0, 0, 0, 0, 0, 0, 0};
        l8 = h8;
      }
      *(short8*)&xhi[(size_t)row * KP + c8] = h8;
      *(short8*)&xlo[(size_t)row * KP + c8] = l8;
    }
    for (int i = tid0; i < M * 128; i += stride)
      ((float4*)qk)[i] = make_float4(0.f, 0.f, 0.f, 0.f);
    return;
  }

  const int id = blockIdx.x - 1024;
  if (id >= 666) return;
  __shared__ float t[64][65];
  const int tx = tid & 63, ty = tid >> 6;

  if (id < 216) {
    const int seg = id / 72;
    const int rem = id - seg * 72;
    const int k0 = (rem >> 3) * 64;
    const int n0 = (rem & 7) * 64;
    for (int rr = ty; rr < 64; rr += 4) {
      int kk = k0 + rr, n = n0 + tx;
      float v = 0.f;
      if (kk < DM) v = (n < 256) ? Wq_lin[(size_t)kk * 256 + n]
                                 : Wk_lin[(size_t)kk * 256 + (n - 256)];
      t[rr][tx] = v;
    }
    __syncthreads();
    for (int cc = ty; cc < 64; cc += 4) {
      int n = n0 + cc, kk = k0 + tx;
      if (kk < KP) {
        float v = t[tx][cc];
        ushort h = f2bf(v);
        if (seg == 2) h = f2bf(v - bf2f(h));
        Wqks[(size_t)n * KSPLIT + seg * KP + kk] = h;
      }
    }
  } else if (id < 513) {
    const int rem = id - 216;
    const int kt = rem / 33, nt = rem - kt * 33;
    const int k0 = kt * 64, n0 = nt * 64;
    for (int rr = ty; rr < 64; rr += 4) {
      int kk = k0 + rr, n = n0 + tx;
      float v = 0.f;
      if (kk < DM) {
        if (n < DM) v = Wq_win[(size_t)kk * DM + n];
        else if (n < 2 * DM) v = Wk_win[(size_t)kk * DM + (n - DM)] * K1C;
        else if (n < 3 * DM) v = Wv_win[(size_t)kk * DM + (n - 2 * DM)];
        else v = Wv_lin[(size_t)kk * DM + (n - 3 * DM)];
      }
      t[rr][tx] = v;
    }
    __syncthreads();
    for (int cc = ty; cc < 64; cc += 4) {
      int n = n0 + cc, kk = k0 + tx;
      if (kk < KP) WprojT[(size_t)n * KP + kk] = f2bf(t[tx][cc]);
    }
  } else {
    const int rem = id - 513;
    const int kt = rem / 9, nt = rem - kt * 9;
    const int k0 = kt * 64, n0 = nt * 64;
    for (int rr = ty; rr < 64; rr += 4) {
      int kk = k0 + rr, n = n0 + tx;
      float v = 0.f;
      if (n < DM && kk < KOUT)
        v = (kk < DM) ? Wo_lin[(size_t)kk * DM + n] : Wo_win[(size_t)(kk - DM) * DM + n];
      t[rr][tx] = v;
    }
    __syncthreads();
    for (int cc = ty; cc < 64; cc += 4) {
      int n = n0 + cc, kk = k0 + tx;
      if (n < DM && kk < KOUT) WoT2[(size_t)n * KOUT + kk] = f2bf(t[tx][cc]);
    }
  }
}

// ---------------- merged projection GEMMs (one launch) ---------------------------
__global__ __launch_bounds__(256) void proj_fused(const ushort* __restrict__ xhi,
                                                  const ushort* __restrict__ xlo,
                                                  const ushort* __restrict__ Wqks,
                                                  const ushort* __restrict__ WprojT,
                                                  float* __restrict__ qk,
                                                  ushort* __restrict__ qkvw,
                                                  float* __restrict__ v_lin,
                                                  const int* __restrict__ maskp,
                                                  int S) {
  __shared__ ushort As[128][36];
  __shared__ ushort Bs[128][36];
  const int bm = blockIdx.x * 128;
  const int tid = threadIdx.x;
  const int lane = tid & 63, w = tid >> 6;
  const int lo = lane & 15, hi = lane >> 4;
  const int wr = w >> 1, wc = w & 1;
  const short8 zv = {0, 0, 0, 0, 0, 0, 0, 0};
  f32x4 acc[4][4];
#pragma unroll
  for (int mb = 0; mb < 4; ++mb)
#pragma unroll
    for (int nb = 0; nb < 4; ++nb) acc[mb][nb] = (f32x4){0.f, 0.f, 0.f, 0.f};

  if (blockIdx.y < 17) {
    const int bn = blockIdx.y * 128;
    for (int k0 = 0; k0 < KP; k0 += 32) {
      short8 a_ld[2], b_ld[2];
#pragma unroll
      for (int p = 0; p < 2; ++p) {
        int c = tid + p * 256;
        int row = c >> 2, cc = c & 3;
        a_ld[p] = *(const short8*)&xhi[(size_t)(bm + row) * KP + k0 + cc * 8];
        int bnr = bn + row;
        b_ld[p] = (bnr < NPROJ) ? *(const short8*)&WprojT[(size_t)bnr * KP + k0 + cc * 8] : zv;
      }
      __syncthreads();
#pragma unroll
      for (int p = 0; p < 2; ++p) {
        int c = tid + p * 256;
        int row = c >> 2, cc = c & 3;
        *(short8*)&As[row][cc * 8] = a_ld[p];
        *(short8*)&Bs[row][cc * 8] = b_ld[p];
      }
      __syncthreads();
      short8 afr[4], bfr[4];
#pragma unroll
      for (int mb = 0; mb < 4; ++mb) afr[mb] = *(const short8*)&As[wr * 64 + 16 * mb + lo][8 * hi];
#pragma unroll
      for (int nb = 0; nb < 4; ++nb) bfr[nb] = *(const short8*)&Bs[wc * 64 + 16 * nb + lo][8 * hi];
#pragma unroll
      for (int mb = 0; mb < 4; ++mb)
#pragma unroll
        for (int nb = 0; nb < 4; ++nb)
          acc[mb][nb] = __builtin_amdgcn_mfma_f32_16x16x32_bf16(afr[mb], bfr[nb], acc[mb][nb], 0, 0, 0);
    }
#pragma unroll
    for (int nb = 0; nb < 4; ++nb) {
      const int col = bn + wc * 64 + 16 * nb + lo;
      if (col >= NPROJ) continue;
      const int seg = col / DM;          // 0=win q 1=win k 2=win v 3=lin v
      const int cc = col - seg * DM;
      if (seg == 3) {
#pragma unroll
        for (int mb = 0; mb < 4; ++mb)
#pragma unroll
          for (int r = 0; r < 4; ++r) {
            int row = bm + wr * 64 + 16 * mb + 4 * hi + r;
            v_lin[(size_t)row * DM + cc] = acc[mb][nb][r];
          }
      } else {
        const uint h = ((uint)cc * 993u) >> 15;
        const int e = cc - (int)h * 33;
        ushort* dst = qkvw + (size_t)seg * (32u * (uint)S * 40u);
#pragma unroll
        for (int mb = 0; mb < 4; ++mb)
#pragma unroll
          for (int r = 0; r < 4; ++r) {
            int row = bm + wr * 64 + 16 * mb + 4 * hi + r;
            int b = (row >= S) ? 1 : 0;
            int nn = row - b * S;
            float val = acc[mb][nb][r];
            if (seg == 2) {
              size_t tb = (size_t)(b * NH + (int)h) * 40;
              dst[(tb + e) * S + nn] = f2bf(val);
              if (e == 0) {
                dst[(tb + 33) * S + nn] = 0x3F80;
#pragma unroll
                for (int z = 34; z < 40; ++z) dst[(tb + z) * S + nn] = 0;
              }
            } else {
              size_t base = ((size_t)(b * NH + (int)h) * S + nn) * 40;
              dst[base + e] = f2bf(val);
              if (e == 0) {
                ushort pad33 = (seg == 0) ? (ushort)0x3F80
                                          : (maskp[row] ? (ushort)0 : f2bf(-1e30f));
                dst[base + 33] = pad33;
#pragma unroll
                for (int z = 34; z < 40; ++z) dst[base + z] = 0;
              }
            }
          }
      }
    }
  } else {
    const int yy = blockIdx.y - 17;      // 0..11
    const int seg = yy >> 2;             // K-segment 0..2
    const int bn = (yy & 3) * 128;
    const ushort* xsrc = (seg == 1) ? xlo : xhi;
    const int kb = seg * KP;
    for (int k0 = 0; k0 < KP; k0 += 32) {
      short8 a_ld[2], b_ld[2];
#pragma unroll
      for (int p = 0; p < 2; ++p) {
        int c = tid + p * 256;
        int row = c >> 2, cc = c & 3;
        a_ld[p] = *(const short8*)&xsrc[(size_t)(bm + row) * KP + k0 + cc * 8];
        b_ld[p] = *(const short8*)&Wqks[(size_t)(bn + row) * KSPLIT + kb + k0 + cc * 8];
      }
      __syncthreads();
#pragma unroll
      for (int p = 0; p < 2; ++p) {
        int c = tid + p * 256;
        int row = c >> 2, cc = c & 3;
        *(short8*)&As[row][cc * 8] = a_ld[p];
        *(short8*)&Bs[row][cc * 8] = b_ld[p];
      }
      __syncthreads();
      short8 afr[4], bfr[4];
#pragma unroll
      for (int mb = 0; mb < 4; ++mb) afr[mb] = *(const short8*)&As[wr * 64 + 16 * mb + lo][8 * hi];
#pragma unroll
      for (int nb = 0; nb < 4; ++nb) bfr[nb] = *(const short8*)&Bs[wc * 64 + 16 * nb + lo][8 * hi];
#pragma unroll
      for (int mb = 0; mb < 4; ++mb)
#pragma unroll
        for (int nb = 0; nb < 4; ++nb)
          acc[mb][nb] = __builtin_amdgcn_mfma_f32_16x16x32_bf16(afr[mb], bfr[nb], acc[mb][nb], 0, 0, 0);
    }
#pragma unroll
    for (int mb = 0; mb < 4; ++mb)
#pragma unroll
      for (int nb = 0; nb < 4; ++nb) {
        int col = bn + wc * 64 + 16 * nb + lo;
#pragma unroll
        for (int r = 0; r < 4; ++r) {
          int row = bm + wr * 64 + 16 * mb + 4 * hi + r;
          atomicAdd(&qk[(size_t)row * 512 + col], acc[mb][nb][r]);
        }
      }
  }
}

// ---------------- final output GEMM: BM=64 x BN=128 ------------------------------
__global__ __launch_bounds__(256) void gemm_out(const ushort* __restrict__ A,
                                                const ushort* __restrict__ Bt,
                                                float* __restrict__ C, int S) {
  __shared__ ushort As[64][36];
  __shared__ ushort Bs[128][36];
  const int bm = blockIdx.x * 64, bn = blockIdx.y * 128;
  const int tid = threadIdx.x;
  const int lane = tid & 63, w = tid >> 6;
  const int lo = lane & 15, hi = lane >> 4;
  const int wr = w & 1, wc = w >> 1;
  f32x4 acc[2][4];
#pragma unroll
  for (int mb = 0; mb < 2; ++mb)
#pragma unroll
    for (int nb = 0; nb < 4; ++nb) acc[mb][nb] = (f32x4){0.f, 0.f, 0.f, 0.f};
  const short8 zv = {0, 0, 0, 0, 0, 0, 0, 0};

  for (int k0 = 0; k0 < KOUT; k0 += 32) {
    short8 a_ld, b_ld[2];
    {
      int row = tid >> 2, cc = tid & 3;
      a_ld = *(const short8*)&A[(size_t)(bm + row) * KOUT + k0 + cc * 8];
    }
#pragma unroll
    for (int p = 0; p < 2; ++p) {
      int c = tid + p * 256;
      int row = c >> 2, cc = c & 3;
      int bnr = bn + row;
      b_ld[p] = (bnr < DM) ? *(const short8*)&Bt[(size_t)bnr * KOUT + k0 + cc * 8] : zv;
    }
    __syncthreads();
    {
      int row = tid >> 2, cc = tid & 3;
      *(short8*)&As[row][cc * 8] = a_ld;
    }
#pragma unroll
    for (int p = 0; p < 2; ++p) {
      int c = tid + p * 256;
      int row = c >> 2, cc = c & 3;
      *(short8*)&Bs[row][cc * 8] = b_ld[p];
    }
    __syncthreads();
    short8 afr[2], bfr[4];
#pragma unroll
    for (int mb = 0; mb < 2; ++mb) afr[mb] = *(const short8*)&As[wr * 32 + 16 * mb + lo][8 * hi];
#pragma unroll
    for (int nb = 0; nb < 4; ++nb) bfr[nb] = *(const short8*)&Bs[wc * 64 + 16 * nb + lo][8 * hi];
#pragma unroll
    for (int mb = 0; mb < 2; ++mb)
#pragma unroll
      for (int nb = 0; nb < 4; ++nb)
        acc[mb][nb] = __builtin_amdgcn_mfma_f32_16x16x32_bf16(afr[mb], bfr[nb], acc[mb][nb], 0, 0, 0);
  }
#pragma unroll
  for (int nb = 0; nb < 4; ++nb) {
    const int col = bn + wc * 64 + 16 * nb + lo;
    if (col >= DM) continue;
#pragma unroll
    for (int mb = 0; mb < 2; ++mb)
#pragma unroll
      for (int r = 0; r < 4; ++r) {
        int row = bm + wr * 32 + 16 * mb + 4 * hi + r;
        C[(size_t)row * DM + col] = acc[mb][nb][r];
      }
  }
}

__global__ __launch_bounds__(256) void lin_red(const float* __restrict__ kvp,
                                               float* __restrict__ kvr) {
  int bh = blockIdx.x;
  for (int i = threadIdx.x; i < 1188; i += 256) {
    float s = 0.f;
#pragma unroll
    for (int c = 0; c < NCH; ++c) s += kvp[(size_t)(bh * NCH + c) * 1188 + i];
    kvr[(size_t)bh * 1188 + i] = s;
  }
}

// ---------------- merged: banded attention (dbuf LDS, 1 barrier/tile) + lin kv ---
__global__ __launch_bounds__(256) void win_kv(const ushort* __restrict__ qwb,
                                              const ushort* __restrict__ kwb,
                                              const ushort* __restrict__ vwbT,
                                              ushort* __restrict__ Opart,
                                              const float* __restrict__ qk,
                                              const float* __restrict__ v_lin,
                                              float* __restrict__ kvp,
                                              int B, int S, int NT2) {
  __shared__ ushort KsS[2][64 * 40];   // 10240 B (linkv: kraw floats 4352 B)
  __shared__ ushort VtS[2][40 * 72];   // 11520 B
  __shared__ ushort PsS[4 * 32 * 40];  // 10240 B (linkv: vsh floats 9216 B)
  const int tid = threadIdx.x;
  const int NWINBLK = NT2 * 32 * ZPARTS;
  const int bx = blockIdx.x;

  if (bx < NWINBLK) {
    // ========== banded attention; bh = bx&31 -> XCD gets 4 fixed bh ==========
    const int bh = bx & 31;
    const int qp = bx >> 5;
    const int part = qp / NT2;
    const int qt = NT2 - 1 - (qp - part * NT2);   // longest first
    const int NT = NT2 * 2;
    const int T = min(NT, 2 * qt + 3);
    if (part >= T) return;
    const int n0 = qt * 128;
    const int lane = tid & 63, w = tid >> 6;
    const int lo = lane & 15, hi = lane >> 4;
    const short8 zv = {0, 0, 0, 0, 0, 0, 0, 0};

    short8 qf[2][2];
#pragma unroll
    for (int qr = 0; qr < 2; ++qr) {
      const ushort* qrow = qwb + ((size_t)bh * S + n0 + w * 32 + qr * 16 + lo) * 40;
      qf[qr][0] = *(const short8*)&qrow[8 * hi];
      qf[qr][1] = (hi == 0) ? *(const short8*)&qrow[32] : zv;
    }

    const ushort* kb = kwb + (size_t)bh * S * 40;
    const ushort* vb = vwbT + (size_t)bh * 40 * S;
    int evc[3];
#pragma unroll
    for (int eb = 0; eb < 3; ++eb) {
      int e = 16 * eb + lo;
      evc[eb] = (e > 39) ? 39 : e;
    }

    const int kr0_row = tid / 5, kr0_cc = tid % 5;
    const bool p1v = (tid < 64);
    const int kr1_row = (tid + 256) / 5, kr1_cc = (tid + 256) % 5;
    const int vr0_e = tid >> 3, vr0_cc = tid & 7;
    const int vr1_e = (tid + 256) >> 3, vr1_cc = (tid + 256) & 7;
    short8 kreg[2], vreg[2];

#define ISSUE(tt) {                                                                   \
      int m0_ = (tt) * 64;                                                            \
      kreg[0] = *(const short8*)&kb[(size_t)(m0_ + kr0_row) * 40 + kr0_cc * 8];       \
      if (p1v) kreg[1] = *(const short8*)&kb[(size_t)(m0_ + kr1_row) * 40 + kr1_cc * 8]; \
      vreg[0] = *(const short8*)&vb[(size_t)vr0_e * S + m0_ + vr0_cc * 8];            \
      if (p1v) vreg[1] = *(const short8*)&vb[(size_t)vr1_e * S + m0_ + vr1_cc * 8]; }

    f32x4 Oacc[2][3];
#pragma unroll
    for (int qr = 0; qr < 2; ++qr)
#pragma unroll
      for (int eb = 0; eb < 3; ++eb) Oacc[qr][eb] = (f32x4){0.f, 0.f, 0.f, 0.f};

    ISSUE(part);
    int c = 0;

    for (int t = part; t < T; t += ZPARTS) {
      // write buf c (prev reads of buf c finished >=1 barrier ago)
      *(short8*)&KsS[c][kr0_row * 40 + kr0_cc * 8] = kreg[0];
      if (p1v) *(short8*)&KsS[c][kr1_row * 40 + kr1_cc * 8] = kreg[1];
      *(short8*)&VtS[c][vr0_e * 72 + vr0_cc * 8] = vreg[0];
      if (p1v) *(short8*)&VtS[c][vr1_e * 72 + vr1_cc * 8] = vreg[1];
      if (t + ZPARTS < T) ISSUE(t + ZPARTS);
      __syncthreads();           // single barrier per tile (dbuf)

      const int m0 = t * 64;

      f32x4 accS[2][4];
#pragma unroll
      for (int qr = 0; qr < 2; ++qr)
#pragma unroll
        for (int bb = 0; bb < 4; ++bb) accS[qr][bb] = (f32x4){0.f, 0.f, 0.f, 0.f};
#pragma unroll
      for (int bb = 0; bb < 4; ++bb) {
        short8 kf0 = *(const short8*)&KsS[c][(16 * bb + lo) * 40 + 8 * hi];
        short8 kf1 = *(const short8*)&KsS[c][(16 * bb + lo) * 40 + 32];
#pragma unroll
        for (int qr = 0; qr < 2; ++qr) {
          accS[qr][bb] = __builtin_amdgcn_mfma_f32_16x16x32_bf16(qf[qr][0], kf0, accS[qr][bb], 0, 0, 0);
          accS[qr][bb] = __builtin_amdgcn_mfma_f32_16x16x32_bf16(qf[qr][1], kf1, accS[qr][bb], 0, 0, 0);
        }
      }

      const bool boundary = (m0 > n0);
      const int dmn = m0 - n0;
#pragma unroll
      for (int qr = 0; qr < 2; ++qr)
#pragma unroll
        for (int bb = 0; bb < 4; ++bb)
#pragma unroll
          for (int r = 0; r < 4; ++r) {
            float p = exp2f(accS[qr][bb][r]);
            if (boundary) {
              int rr = w * 32 + qr * 16 + 4 * hi + r;
              int cq = 16 * bb + lo;
              if (cq > rr + 63 - dmn) p = 0.f;
            }
            PsS[(w * 32 + qr * 16 + 4 * hi + r) * 40 + 16 * bb + lo] = f2bf_tr(p);
          }

#pragma unroll
      for (int qr = 0; qr < 2; ++qr) {
        short8 pf0 = *(const short8*)&PsS[(w * 32 + qr * 16 + lo) * 40 + 8 * hi];
        short8 pf1 = *(const short8*)&PsS[(w * 32 + qr * 16 + lo) * 40 + 32];
#pragma unroll
        for (int eb = 0; eb < 3; ++eb) {
          short8 vf0 = *(const short8*)&VtS[c][evc[eb] * 72 + 8 * hi];
          short8 vf1 = *(const short8*)&VtS[c][evc[eb] * 72 + 32 + 8 * hi];
          Oacc[qr][eb] = __builtin_amdgcn_mfma_f32_16x16x32_bf16(pf0, vf0, Oacc[qr][eb], 0, 0, 0);
          Oacc[qr][eb] = __builtin_amdgcn_mfma_f32_16x16x32_bf16(pf1, vf1, Oacc[qr][eb], 0, 0, 0);
        }
      }
      c ^= 1;
    }
#undef ISSUE

    const size_t ob = ((size_t)(bh * NT2 + qt) * ZPARTS + part) * OPS;
#pragma unroll
    for (int qr = 0; qr < 2; ++qr)
#pragma unroll
      for (int eb = 0; eb < 3; ++eb) {
        int e = 16 * eb + lo;
        if (e < 34) {
#pragma unroll
          for (int r = 0; r < 4; ++r)
            Opart[ob + (size_t)(w * 32 + qr * 16 + 4 * hi + r) * 34 + e] = f2bf(Oacc[qr][eb][r]);
        }
      }
  } else {
    // ========== linear-attention kv partials ==========
    const int idx = bx - NWINBLK;
    const int bh = idx & 31, chunk = idx >> 5;
    const int b = bh >> 4, h = bh & 15;
    float* kraw = (float*)KsS;                   // [64][17]
    float* vsh = (float*)PsS;                    // [64][36]
    if (tid < 64) { vsh[tid * 36 + 33] = 1.f; vsh[tid * 36 + 34] = 0.f; vsh[tid * 36 + 35] = 0.f; }
    f32x4 acc0 = {0.f, 0.f, 0.f, 0.f}, acc1 = {0.f, 0.f, 0.f, 0.f};
    const int d0 = tid / 9, c40 = (tid % 9) * 4;
    const int idx1 = tid + 256;
    const int d1 = idx1 / 9, c41 = (idx1 % 9) * 4;
    const int SC = S / NCH;
    const int nbeg = chunk * SC;
    __syncthreads();
    for (int n0 = nbeg; n0 < nbeg + SC; n0 += 64) {
      {
        int row = tid >> 2, f4 = (tid & 3) * 4;
        float4 kv4 = *(const float4*)&qk[(size_t)(b * S + n0 + row) * 512 + 256 + h * 16 + f4];
        kraw[row * 17 + f4 + 0] = kv4.x; kraw[row * 17 + f4 + 1] = kv4.y;
        kraw[row * 17 + f4 + 2] = kv4.z; kraw[row * 17 + f4 + 3] = kv4.w;
      }
      for (int i = tid; i < 64 * 33; i += 256) {
        int n = i / 33, e = i - n * 33;
        vsh[n * 36 + e] = v_lin[(size_t)(b * S + n0 + n) * DM + h * HD + e];
      }
      __syncthreads();
#pragma unroll 4
      for (int n = 0; n < 64; ++n) {
        {
          float ke;
          if (d0 == 0) ke = 1.f;
          else if (d0 < 17) ke = kraw[n * 17 + d0 - 1];
          else { float kk = kraw[n * 17 + d0 - 17]; ke = 0.5f * kk * kk; }
          f32x4 v = *(const f32x4*)&vsh[n * 36 + c40];
          acc0 += ke * v;
        }
        if (idx1 < 297) {
          float ke;
          if (d1 < 17) ke = kraw[n * 17 + d1 - 1];
          else { float kk = kraw[n * 17 + d1 - 17]; ke = 0.5f * kk * kk; }
          f32x4 v = *(const f32x4*)&vsh[n * 36 + c41];
          acc1 += ke * v;
        }
      }
      __syncthreads();
    }
    float* dst = kvp + (size_t)(bh * NCH + chunk) * 1188;
    *(f32x4*)&dst[d0 * 36 + c40] = acc0;
    if (idx1 < 297) *(f32x4*)&dst[d1 * 36 + c41] = acc1;
  }
}

// ---------------- merged: combine partials + linear output -> cat ----------------
__global__ __launch_bounds__(256) void comb_lin(const ushort* __restrict__ Opart,
                                                const float* __restrict__ qk,
                                                const float* __restrict__ kvr,
                                                const int* __restrict__ mask,
                                                ushort* __restrict__ cat,
                                                int B, int S, int NT2) {
  __shared__ float shf[160];
  const int tid = threadIdx.x;
  const int NCOMB = NT2 * 32;
  const int bx = blockIdx.x;

  if (bx < NCOMB) {
    const int bh = bx & 31;
    const int qt = bx >> 5;
    const int b = bh >> 4, h = bh & 15;
    const int T = min(NT2 * 2, 2 * qt + 3);
    const int P = min(ZPARTS, T);
    const size_t base = (size_t)(bh * NT2 + qt) * ZPARTS * OPS;
    float* linv = shf;
    if (tid < 128) {
      float l = 0.f;
      for (int p = 0; p < P; ++p) l += bf2f(Opart[base + (size_t)p * OPS + tid * 34 + 33]);
      linv[tid] = (l > 0.f) ? 1.f / l : 0.f;
    }
    __syncthreads();
    for (int i = tid; i < 128 * 33; i += 256) {
      int row = i / 33, e = i - row * 33;
      float o = 0.f;
      for (int p = 0; p < P; ++p) o += bf2f(Opart[base + (size_t)p * OPS + row * 34 + e]);
      int n = qt * 128 + row;
      cat[((size_t)(b * S + n)) * KOUT + DM + h * HD + e] = f2bf(o * linv[row]);
    }
  } else {
    const int bs = bx - NCOMB;
    const int b = (bs >= S) ? 1 : 0;
    __shared__ float qsh2[NH * 17];
    float* qsh = qsh2;
    for (int i = tid; i < NH * FEAT; i += 256)
      qsh[(i >> 4) * 17 + (i & 15)] = qk[(size_t)bs * 512 + i];
    __syncthreads();
    const int msk = mask[bs];
    for (int o = tid; o < DM; o += 256) {
      uint h = ((uint)o * 993u) >> 15;
      int e = o - (int)h * 33;
      const float* kvh = kvr + (size_t)(b * NH + (int)h) * 1188;
      float qsum = 1.f, qkv = kvh[e];
#pragma unroll
      for (int f = 0; f < FEAT; ++f) {
        float q = qsh[h * 17 + f];
        float q2 = 0.5f * q * q;
        qsum += q + q2;
        qkv += q * kvh[(1 + f) * 36 + e] + q2 * kvh[(17 + f) * 36 + e];
      }
      float z = qsum * kvh[e * 36 + 33];
      float outv = qkv / (z + EPSF);
      if (msk == 0) outv = 0.f;
      cat[(size_t)bs * KOUT + o] = f2bf(outv);
    }
  }
}

extern "C" void kernel_launch(void* const* d_in, const int* in_sizes, int n_in,
                              void* d_out, int out_size, void* d_ws, size_t ws_size,
                              hipStream_t stream) {
  const float* x      = (const float*)d_in[0];
  const int*   mask   = (const int*)d_in[1];
  const float* Wq_lin = (const float*)d_in[2];
  const float* Wk_lin = (const float*)d_in[3];
  const float* Wv_lin = (const float*)d_in[4];
  const float* Wo_lin = (const float*)d_in[5];
  const float* Wq_win = (const float*)d_in[6];
  const float* Wk_win = (const float*)d_in[7];
  const float* Wv_win = (const float*)d_in[8];
  const float* Wo_win = (const float*)d_in[9];
  float* out = (float*)d_out;

  const int BS = in_sizes[1];
  const int B = 2;
  const int S = BS / B;
  const int NT2 = S / 128;
  const int M = BS;

  // fp32 workspace
  float* ws = (float*)d_ws;
  float* qk      = ws;  ws += (size_t)BS * 512;
  float* v_lin   = ws;  ws += (size_t)BS * DM;
  float* kvp     = ws;  ws += (size_t)B * NH * NCH * 1188;
  float* kvr     = ws;  ws += (size_t)B * NH * 1188;
  // bf16 workspace
  ushort* ub     = (ushort*)ws;
  ushort* x_hi   = ub;  ub += (size_t)M * KP;
  ushort* x_lo   = ub;  ub += (size_t)M * KP;
  ushort* qkvw   = ub;  ub += (size_t)3 * 32 * S * 40;    // q | k | vT contiguous
  ushort* cat    = ub;  ub += (size_t)M * KOUT;
  ushort* WprojT = ub;  ub += (size_t)NPROJ * KP;
  ushort* WoT2   = ub;  ub += (size_t)DM * KOUT;
  ushort* Wqks   = ub;  ub += (size_t)512 * KSPLIT;
  ushort* Opart  = ub;  ub += (size_t)32 * NT2 * ZPARTS * OPS;

  ushort* qwb  = qkvw;
  ushort* kwb  = qkvw + (size_t)32 * S * 40;
  ushort* vwbT = qkvw + (size_t)64 * S * 40;

  dim3 blk(256);

  prep_all<<<1690, blk, 0, stream>>>(x, Wq_lin, Wk_lin, Wv_lin, Wo_lin,
                                     Wq_win, Wk_win, Wv_win, Wo_win,
                                     x_hi, x_lo, Wqks, WprojT, WoT2, qk, M);

  // merged: win/linv projection (y<17) + lin q/k split GEMM by K-segment (y 17..28)
  proj_fused<<<dim3(M / 128, 29), blk, 0, stream>>>(x_hi, x_lo, Wqks, WprojT,
                                                    qk, qkvw, v_lin, mask, S);

  // merged: banded attention (XCD-pinned, dbuf LDS, 1 barrier/tile) + lin kv partials
  win_kv<<<dim3(NT2 * 32 * ZPARTS + B * NH * NCH), blk, 0, stream>>>(
      qwb, kwb, vwbT, Opart, qk, v_lin, kvp, B, S, NT2);

  lin_red<<<dim3(B * NH), blk, 0, stream>>>(kvp, kvr);

  // merged: combine + lin output
  comb_lin<<<dim3(NT2 * 32 + BS), blk, 0, stream>>>(Opart, qk, kvr, mask, cat, B, S, NT2);

  gemm_out<<<dim3(M / 64, (DM + 127) / 128), blk, 0, stream>>>(cat, WoT2, out, S);
}